// Round 4
// baseline (116.670 us; speedup 1.0000x reference)
//
#include <hip/hip_runtime.h>
#include <hip/hip_bf16.h>
#include <stdint.h>

typedef __attribute__((ext_vector_type(8))) short  s16x8;
typedef __attribute__((ext_vector_type(8))) __bf16 bf16x8;
typedef __attribute__((ext_vector_type(4))) float  f32x4;

#define N_ROWS  32768   // 64 * 512
#define N_CODES 1024
#define DIM     512
#define BK      64
#define NT      (DIM / BK)   // 8 K-tiles

static __device__ __forceinline__ short f2bf(float f) {
    unsigned u = __float_as_uint(f);
    u += 0x7fffu + ((u >> 16) & 1u);   // round-to-nearest-even
    return (short)(u >> 16);
}

typedef const __attribute__((address_space(1))) uint32_t guint;
typedef __attribute__((address_space(3))) uint32_t luint;
static __device__ __forceinline__ void gl_lds16(const short* g, short* l) {
    __builtin_amdgcn_global_load_lds((guint*)g, (luint*)l, 16, 0, 0);
}

// ---------------- K0a: convert X to bf16 ----------------
__global__ void __launch_bounds__(256)
convertX(const float* __restrict__ X, short* __restrict__ Xb) {
    const size_t i = ((size_t)blockIdx.x * 256 + threadIdx.x) * 8;
    float4 a = *(const float4*)(X + i);
    float4 b = *(const float4*)(X + i + 4);
    s16x8 v = { f2bf(a.x), f2bf(a.y), f2bf(a.z), f2bf(a.w),
                f2bf(b.x), f2bf(b.y), f2bf(b.z), f2bf(b.w) };
    *(s16x8*)(Xb + i) = v;
}

// ---------------- K0b: convert W to bf16 + codebook norms ----------------
__global__ void __launch_bounds__(256)
convertW(const float* __restrict__ W, short* __restrict__ Wb,
         float* __restrict__ wnorm) {
    const int lane = threadIdx.x & 63;
    const int code = blockIdx.x * 4 + (threadIdx.x >> 6);
    const float4* wp = (const float4*)(W + (size_t)code * DIM + lane * 8);
    float4 a = wp[0], b = wp[1];
    s16x8 v = { f2bf(a.x), f2bf(a.y), f2bf(a.z), f2bf(a.w),
                f2bf(b.x), f2bf(b.y), f2bf(b.z), f2bf(b.w) };
    *(s16x8*)(Wb + (size_t)code * DIM + lane * 8) = v;
    float s = a.x*a.x + a.y*a.y + a.z*a.z + a.w*a.w
            + b.x*b.x + b.y*b.y + b.z*b.z + b.w*b.w;
    #pragma unroll
    for (int d = 1; d < 64; d <<= 1) s += __shfl_xor(s, d);
    if (lane == 0) wnorm[code] = s;
}

// ---------------- K2: 256x256 8-phase MFMA GEMM + argmin ----------------
// 8 waves (2M x 4N), BK=64, 128KB LDS dbuf. Wave output 128x64 split across
// halves: rows wr*64+mh*128, cols wc*32+nh*128 -> each quadrant-phase reads
// exactly one A-half and one B-half, enabling tile t+2 prefetch into the
// live buffer after the half's last reader. Counted vmcnt(4) gate per tile.
__global__ void __launch_bounds__(512, 2)
gemm_argmin(const short* __restrict__ Xb, const short* __restrict__ Wb,
            const float* __restrict__ wnorm, float2* __restrict__ pairs) {
    __shared__ __align__(16) short As[2][256 * 64];
    __shared__ __align__(16) short Bs[2][256 * 64];

    const int tid  = threadIdx.x;
    const int lane = tid & 63;
    const int wave = tid >> 6;
    const int wr = wave >> 2, wc = wave & 3;
    const int lr = lane & 15, kg = lane >> 4;

    // XCD-chunked swizzle (512 wgs, 64/XCD): XCD x -> colTile x>>1.
    const int sid = (blockIdx.x & 7) * 64 + (blockIdx.x >> 3);
    const int colBase = (sid >> 7) * 256;   // 4 col-tiles
    const int rowBase = (sid & 127) * 256;  // 128 row-tiles

    // staging: thread -> (row sr + j*64, dest slot tid&7), source slot XOR'd
    const int sr = tid >> 3;                       // 0..63
    const int sq = ((tid & 7) ^ (sr & 7)) * 8;     // pre-swizzled src (shorts)
    const int dq = (tid & 7) * 8;                  // linear LDS dest
    const short* aBase = Xb + (size_t)rowBase * DIM;
    const short* bBase = Wb + (size_t)colBase * DIM;

#define STAGE_A(buf, tt, h) do {                                              \
    gl_lds16(aBase + (size_t)((h)*128 +      sr) * DIM + (tt)*BK + sq,        \
             &As[buf][((h)*128 +      sr)*64 + dq]);                          \
    gl_lds16(aBase + (size_t)((h)*128 + 64 + sr) * DIM + (tt)*BK + sq,        \
             &As[buf][((h)*128 + 64 + sr)*64 + dq]);                          \
  } while (0)
#define STAGE_B(buf, tt, h) do {                                              \
    gl_lds16(bBase + (size_t)((h)*128 +      sr) * DIM + (tt)*BK + sq,        \
             &Bs[buf][((h)*128 +      sr)*64 + dq]);                          \
    gl_lds16(bBase + (size_t)((h)*128 + 64 + sr) * DIM + (tt)*BK + sq,        \
             &Bs[buf][((h)*128 + 64 + sr)*64 + dq]);                          \
  } while (0)

    f32x4 acc[8][4];
    #pragma unroll
    for (int m = 0; m < 8; ++m)
        #pragma unroll
        for (int n = 0; n < 4; ++n) acc[m][n] = (f32x4)0.f;

    // swizzled ds_read slot offsets (shorts): slot = (ks*4+kg) ^ (lr&7)
    const int sF0 = ((lr >> 2) & 1) * 32 + ((kg ^ (lr & 3)) * 8);
    const int sF1 = sF0 ^ 32;
    const int aRow = wr * 64 + lr;   // + mh*128 + mm*16
    const int bRow = wc * 32 + lr;   // + nh*128 + nn*16

    bf16x8 aF[4][2], bF[4][2];

#define LOAD_A(c, mh) do { _Pragma("unroll")                                  \
    for (int mm = 0; mm < 4; ++mm) {                                          \
      aF[mm][0] = __builtin_bit_cast(bf16x8,                                  \
          *(const s16x8*)&As[c][((mh)*128 + aRow + mm*16)*64 + sF0]);         \
      aF[mm][1] = __builtin_bit_cast(bf16x8,                                  \
          *(const s16x8*)&As[c][((mh)*128 + aRow + mm*16)*64 + sF1]); } } while (0)
#define LOAD_B(c, nh) do { _Pragma("unroll")                                  \
    for (int nn = 0; nn < 2; ++nn) {                                          \
      bF[(nh)*2+nn][0] = __builtin_bit_cast(bf16x8,                           \
          *(const s16x8*)&Bs[c][((nh)*128 + bRow + nn*16)*64 + sF0]);         \
      bF[(nh)*2+nn][1] = __builtin_bit_cast(bf16x8,                           \
          *(const s16x8*)&Bs[c][((nh)*128 + bRow + nn*16)*64 + sF1]); } } while (0)

#define MFMA_Q(mh, nh) do { _Pragma("unroll")                                 \
    for (int mm = 0; mm < 4; ++mm) { _Pragma("unroll")                        \
    for (int nn = 0; nn < 2; ++nn) { _Pragma("unroll")                        \
    for (int ks = 0; ks < 2; ++ks)                                            \
      acc[(mh)*4+mm][(nh)*2+nn] = __builtin_amdgcn_mfma_f32_16x16x32_bf16(    \
          aF[mm][ks], bF[(nh)*2+nn][ks], acc[(mh)*4+mm][(nh)*2+nn], 0,0,0);   \
    } } } while (0)

    // prologue: tile0 all 4 halves + tile1 A0,B0 (12 loads); wait tile0.
    STAGE_A(0, 0, 0); STAGE_B(0, 0, 0); STAGE_A(0, 0, 1); STAGE_B(0, 0, 1);
    STAGE_A(1, 1, 0); STAGE_B(1, 1, 0);
    asm volatile("s_waitcnt vmcnt(4)" ::: "memory");
    __builtin_amdgcn_s_barrier();

    #pragma unroll
    for (int tt = 0; tt < NT; ++tt) {
        const int c = tt & 1;
        // P1 (mh0, nh0): reads A0,B0; stage (t+1)A1 -> other buf (safe).
        LOAD_A(c, 0); LOAD_B(c, 0);
        if (tt + 1 < NT) STAGE_A(c ^ 1, tt + 1, 1);
        __builtin_amdgcn_s_barrier();
        __builtin_amdgcn_s_setprio(1); MFMA_Q(0, 0); __builtin_amdgcn_s_setprio(0);
        __builtin_amdgcn_s_barrier();
        // P2 (mh0, nh1): reads B1 (A0 frags reused); stage (t+1)B1.
        LOAD_B(c, 1);
        if (tt + 1 < NT) STAGE_B(c ^ 1, tt + 1, 1);
        __builtin_amdgcn_s_barrier();
        __builtin_amdgcn_s_setprio(1); MFMA_Q(0, 1); __builtin_amdgcn_s_setprio(0);
        __builtin_amdgcn_s_barrier();
        // P3 (mh1, nh0): reads A1; stage (t+2)A0 into live buf — A0 of t
        // last read in P1, separated by two barriers. SAFE.
        LOAD_A(c, 1);
        if (tt + 2 < NT) STAGE_A(c, tt + 2, 0);
        __builtin_amdgcn_s_barrier();
        __builtin_amdgcn_s_setprio(1); MFMA_Q(1, 0); __builtin_amdgcn_s_setprio(0);
        __builtin_amdgcn_s_barrier();
        // P4 (mh1, nh1): all frags in regs; stage (t+2)B0 (B0 last read P1).
        if (tt + 2 < NT) STAGE_B(c, tt + 2, 0);
        __builtin_amdgcn_s_barrier();
        __builtin_amdgcn_s_setprio(1); MFMA_Q(1, 1); __builtin_amdgcn_s_setprio(0);
        // gate: tile t+1 halves must be landed; (t+2)A0,B0 stay in flight.
        if (tt < NT - 2)       asm volatile("s_waitcnt vmcnt(4)" ::: "memory");
        else if (tt == NT - 2) asm volatile("s_waitcnt vmcnt(0)" ::: "memory");
        __builtin_amdgcn_s_barrier();
    }
#undef STAGE_A
#undef STAGE_B
#undef LOAD_A
#undef LOAD_B
#undef MFMA_Q

    // Epilogue: score = wnorm[col] - 2*dot; per-row argmin per 32-col chunk.
    float wn[4]; int wcol[4];
    #pragma unroll
    for (int n = 0; n < 4; ++n) {
        wcol[n] = colBase + (n >> 1) * 128 + wc * 32 + (n & 1) * 16 + lr;
        wn[n] = wnorm[wcol[n]];
    }
    const int cb32 = colBase >> 5;
    #pragma unroll
    for (int m = 0; m < 8; ++m) {
        const int rowB = rowBase + (m >> 2) * 128 + wr * 64 + (m & 3) * 16 + kg * 4;
        #pragma unroll
        for (int r = 0; r < 4; ++r) {
            #pragma unroll
            for (int nh = 0; nh < 2; ++nh) {
                float bv = wn[nh*2] - 2.0f * acc[m][nh*2][r];
                int   bi = wcol[nh*2];
                float sc = wn[nh*2+1] - 2.0f * acc[m][nh*2+1][r];
                if (sc < bv) { bv = sc; bi = wcol[nh*2+1]; }
                #pragma unroll
                for (int d = 1; d < 16; d <<= 1) {
                    float ov = __shfl_xor(bv, d);
                    int   oi = __shfl_xor(bi, d);
                    if (ov < bv || (ov == bv && oi < bi)) { bv = ov; bi = oi; }
                }
                if (lr == 0)
                    pairs[(size_t)(rowB + r) * 32 + cb32 + nh * 4 + wc] =
                        make_float2(bv, __int_as_float(bi));
            }
        }
    }
}

// ---------------- K3: combine 32 chunk-minima, exact f32 row loss ----------------
__global__ void __launch_bounds__(256)
combine_loss(const float* __restrict__ X, const float* __restrict__ W,
             const float2* __restrict__ pairs, float* __restrict__ partial) {
    __shared__ float psum[4];
    const int lane = threadIdx.x & 63;
    const int wv   = threadIdx.x >> 6;
    const int row  = blockIdx.x * 4 + wv;
    float bv; int bi;
    if (lane < 32) {
        float2 p = pairs[(size_t)row * 32 + lane];
        bv = p.x; bi = __float_as_int(p.y);
    } else {
        bv = __int_as_float(0x7f800000);  // +inf
        bi = 0x7fffffff;
    }
    #pragma unroll
    for (int d = 1; d < 64; d <<= 1) {
        float ov = __shfl_xor(bv, d);
        int   oi = __shfl_xor(bi, d);
        if (ov < bv || (ov == bv && oi < bi)) { bv = ov; bi = oi; }
    }
    const float4* xp = (const float4*)(X + (size_t)row * DIM + lane * 8);
    const float4* wp = (const float4*)(W + (size_t)bi  * DIM + lane * 8);
    float4 x0 = xp[0], x1 = xp[1];
    float4 w0 = wp[0], w1 = wp[1];
    float s = 0.f, d0;
    d0 = x0.x - w0.x; s += d0*d0;  d0 = x0.y - w0.y; s += d0*d0;
    d0 = x0.z - w0.z; s += d0*d0;  d0 = x0.w - w0.w; s += d0*d0;
    d0 = x1.x - w1.x; s += d0*d0;  d0 = x1.y - w1.y; s += d0*d0;
    d0 = x1.z - w1.z; s += d0*d0;  d0 = x1.w - w1.w; s += d0*d0;
    #pragma unroll
    for (int d = 1; d < 64; d <<= 1) s += __shfl_xor(s, d);
    if (lane == 0) psum[wv] = s;
    __syncthreads();
    if (threadIdx.x == 0)
        partial[blockIdx.x] = psum[0] + psum[1] + psum[2] + psum[3];
}

// ---------------- K4: final mean over 8192 partials (double accum) ----------------
__global__ void __launch_bounds__(256)
finalize(const float* __restrict__ partial, float* __restrict__ out) {
    __shared__ double sm[256];
    const float4* p = (const float4*)partial;   // 2048 float4s
    double s = 0.0;
    #pragma unroll
    for (int i = 0; i < 8; ++i) {
        float4 v = p[threadIdx.x + i * 256];
        s += (double)v.x + (double)v.y + (double)v.z + (double)v.w;
    }
    sm[threadIdx.x] = s;
    __syncthreads();
    for (int st = 128; st > 0; st >>= 1) {
        if (threadIdx.x < st) sm[threadIdx.x] += sm[threadIdx.x + st];
        __syncthreads();
    }
    if (threadIdx.x == 0)
        out[0] = (float)(sm[0] / (double)((size_t)N_ROWS * DIM));
}

extern "C" void kernel_launch(void* const* d_in, const int* in_sizes, int n_in,
                              void* d_out, int out_size, void* d_ws, size_t ws_size,
                              hipStream_t stream) {
    const float* X = (const float*)d_in[0];   // [32768][512]
    const float* W = (const float*)d_in[1];   // [1024][512]
    char* ws = (char*)d_ws;
    short*  Xb      = (short*)ws;                          // 32 MB @ 0
    short*  Wb      = (short*)(ws + 33554432);             // 1 MB
    float*  wnorm   = (float*)(ws + 34603008);             // 4 KB
    float2* pairs   = (float2*)(ws + 34607104);            // 8 MB
    float*  partial = (float*)(ws + 42995712);             // 32 KB
    float*  out     = (float*)d_out;

    convertX<<<N_ROWS * DIM / (256 * 8), 256, 0, stream>>>(X, Xb);
    convertW<<<N_CODES / 4, 256, 0, stream>>>(W, Wb, wnorm);
    gemm_argmin<<<512, 512, 0, stream>>>(Xb, Wb, wnorm, pairs);
    combine_loss<<<N_ROWS / 4, 256, 0, stream>>>(X, W, pairs, partial);
    finalize<<<1, 256, 0, stream>>>(partial, out);
}

// Round 5
// 102.978 us; speedup vs baseline: 1.1330x; 1.1330x over previous
//
#include <hip/hip_runtime.h>
#include <hip/hip_bf16.h>
#include <stdint.h>

typedef __attribute__((ext_vector_type(8)))  short  s16x8;
typedef __attribute__((ext_vector_type(8)))  __bf16 bf16x8;
typedef __attribute__((ext_vector_type(16))) float  f32x16;

#define N_ROWS  32768   // 64 * 512
#define N_CODES 1024
#define DIM     512
#define BK      32      // K-tile

static __device__ __forceinline__ short f2bf(float f) {
    unsigned u = __float_as_uint(f);
    u += 0x7fffu + ((u >> 16) & 1u);   // round-to-nearest-even
    return (short)(u >> 16);
}
static __device__ __forceinline__ float bf2f(short h) {
    return __uint_as_float(((unsigned)(unsigned short)h) << 16);
}

typedef const __attribute__((address_space(1))) uint32_t guint;
typedef __attribute__((address_space(3))) uint32_t luint;
static __device__ __forceinline__ void gl_lds16(const short* g, short* l) {
    __builtin_amdgcn_global_load_lds((guint*)g, (luint*)l, 16, 0, 0);
}

// ---------------- K0a: convert X to bf16 ----------------
__global__ void __launch_bounds__(256)
convertX(const float* __restrict__ X, short* __restrict__ Xb) {
    const size_t i = ((size_t)blockIdx.x * 256 + threadIdx.x) * 8;
    float4 a = *(const float4*)(X + i);
    float4 b = *(const float4*)(X + i + 4);
    s16x8 v = { f2bf(a.x), f2bf(a.y), f2bf(a.z), f2bf(a.w),
                f2bf(b.x), f2bf(b.y), f2bf(b.z), f2bf(b.w) };
    *(s16x8*)(Xb + i) = v;
}

// ---------------- K0b: convert W to bf16 + codebook norms ----------------
__global__ void __launch_bounds__(256)
convertW(const float* __restrict__ W, short* __restrict__ Wb,
         float* __restrict__ wnorm) {
    const int lane = threadIdx.x & 63;
    const int code = blockIdx.x * 4 + (threadIdx.x >> 6);
    const float4* wp = (const float4*)(W + (size_t)code * DIM + lane * 8);
    float4 a = wp[0], b = wp[1];
    s16x8 v = { f2bf(a.x), f2bf(a.y), f2bf(a.z), f2bf(a.w),
                f2bf(b.x), f2bf(b.y), f2bf(b.z), f2bf(b.w) };
    *(s16x8*)(Wb + (size_t)code * DIM + lane * 8) = v;
    float s = a.x*a.x + a.y*a.y + a.z*a.z + a.w*a.w
            + b.x*b.x + b.y*b.y + b.z*b.z + b.w*b.w;
    #pragma unroll
    for (int d = 1; d < 64; d <<= 1) s += __shfl_xor(s, d);
    if (lane == 0) wnorm[code] = s;
}

// ---------------- K2: bf16 MFMA GEMM (32x32x16) + per-tile argmin ----------------
// 128x128 tile, BK=32, single 16KB LDS, 4 waves (2x2), wave = 64x64 =
// 2x2 MFMA tiles of 32x32. Slot swizzle p = q ^ ((row>>1)&3): pre-swizzled
// global source (stage) + swizzled ds_read (consume) -> 2-way residual (free).
// XCD row-chunk swizzle: XCD x owns X rows [x*4096, x*4096+4096) (4MB, its
// L2) and sweeps col-blocks within the resident window -> staging hits L2.
__global__ void __launch_bounds__(256)
gemm_argmin(const short* __restrict__ Xb, const short* __restrict__ Wb,
            const float* __restrict__ wnorm, float2* __restrict__ pairs) {
    __shared__ __align__(16) short As[128 * BK];
    __shared__ __align__(16) short Bs[128 * BK];

    const int tid  = threadIdx.x;
    const int lane = tid & 63;
    const int wave = tid >> 6;
    const int wr = wave >> 1, wc = wave & 1;
    const int l31 = lane & 31, lh = lane >> 5;
    const int fsw = (lane >> 1) & 3;          // read-side slot XOR

    // bid = x + 8*(c + 8*rl): xcd x, colBlk c, local rowBlk rl
    const int bid = blockIdx.x;
    const int colBase = ((bid >> 3) & 7) * 128;
    const int rowBase = ((bid & 7) * 32 + (bid >> 6)) * 128;

    // staging: wave stages 32 rows of each tile; lane -> row (lane>>2),
    // phys slot (lane&3); source k pre-swizzled by f(row) = (lane>>3)&3.
    const int ssw = ((lane & 3) ^ ((lane >> 3) & 3)) * 8;
    const short* aSrc = Xb + (size_t)(rowBase + wave*32 + (lane >> 2)) * DIM + ssw;
    const short* bSrc = Wb + (size_t)(colBase + wave*32 + (lane >> 2)) * DIM + ssw;
    short* aDst = &As[wave * 1024 + lane * 8];
    short* bDst = &Bs[wave * 1024 + lane * 8];

    f32x16 acc00 = (f32x16)0.f, acc01 = (f32x16)0.f;
    f32x16 acc10 = (f32x16)0.f, acc11 = (f32x16)0.f;

    const int ar0 = (wr*64      + l31) * BK;
    const int ar1 = (wr*64 + 32 + l31) * BK;
    const int br0 = (wc*64      + l31) * BK;
    const int br1 = (wc*64 + 32 + l31) * BK;

    for (int t = 0; t < DIM / BK; ++t) {
        gl_lds16(aSrc + t * BK,            aDst);
        gl_lds16(aSrc + 16 * DIM + t * BK, aDst + 512);
        gl_lds16(bSrc + t * BK,            bDst);
        gl_lds16(bSrc + 16 * DIM + t * BK, bDst + 512);
        __syncthreads();

        #pragma unroll
        for (int ks = 0; ks < 2; ++ks) {
            const int qo = ((ks * 2 + lh) ^ fsw) * 8;   // swizzled slot (shorts)
            bf16x8 a0 = __builtin_bit_cast(bf16x8, *(const s16x8*)&As[ar0 + qo]);
            bf16x8 a1 = __builtin_bit_cast(bf16x8, *(const s16x8*)&As[ar1 + qo]);
            bf16x8 b0 = __builtin_bit_cast(bf16x8, *(const s16x8*)&Bs[br0 + qo]);
            bf16x8 b1 = __builtin_bit_cast(bf16x8, *(const s16x8*)&Bs[br1 + qo]);
            acc00 = __builtin_amdgcn_mfma_f32_32x32x16_bf16(a0, b0, acc00, 0, 0, 0);
            acc01 = __builtin_amdgcn_mfma_f32_32x32x16_bf16(a0, b1, acc01, 0, 0, 0);
            acc10 = __builtin_amdgcn_mfma_f32_32x32x16_bf16(a1, b0, acc10, 0, 0, 0);
            acc11 = __builtin_amdgcn_mfma_f32_32x32x16_bf16(a1, b1, acc11, 0, 0, 0);
        }
        __syncthreads();
    }

    // Epilogue: score = wnorm[col] - 2*dot. C/D: col = lane&31,
    // row = mi*32 + 4*lh + (reg&3) + 8*(reg>>2). Reduce over 32 lanes.
    float wnv[2]; int wcolv[2];
    #pragma unroll
    for (int ni = 0; ni < 2; ++ni) {
        wcolv[ni] = colBase + wc*64 + ni*32 + l31;
        wnv[ni] = wnorm[wcolv[ni]];
    }
    const int chunk = (colBase >> 6) + wc;   // 0..15

#define ARGMIN_TILE(mi, A0, A1) do {                                          \
    _Pragma("unroll")                                                         \
    for (int reg = 0; reg < 16; ++reg) {                                      \
        float bv = wnv[0] - 2.0f * (A0)[reg];                                 \
        int   bi = wcolv[0];                                                  \
        float sc = wnv[1] - 2.0f * (A1)[reg];                                 \
        if (sc < bv || (sc == bv && wcolv[1] < bi)) { bv = sc; bi = wcolv[1]; } \
        _Pragma("unroll")                                                     \
        for (int d = 1; d < 32; d <<= 1) {                                    \
            float ov = __shfl_xor(bv, d);                                     \
            int   oi = __shfl_xor(bi, d);                                     \
            if (ov < bv || (ov == bv && oi < bi)) { bv = ov; bi = oi; }       \
        }                                                                     \
        if (l31 == 0) {                                                       \
            const int row = rowBase + wr*64 + (mi)*32 + 4*lh                  \
                          + (reg & 3) + 8*(reg >> 2);                         \
            pairs[(size_t)row * 16 + chunk] = make_float2(bv, __int_as_float(bi)); \
        }                                                                     \
    } } while (0)

    ARGMIN_TILE(0, acc00, acc01);
    ARGMIN_TILE(1, acc10, acc11);
#undef ARGMIN_TILE
}

// ---------------- K3: combine 16 chunk-minima, bf16 row loss (f32 accum) ----------------
__global__ void __launch_bounds__(256)
combine_loss(const short* __restrict__ Xb, const short* __restrict__ Wb,
             const float2* __restrict__ pairs, float* __restrict__ partial) {
    __shared__ float psum[4];
    const int lane = threadIdx.x & 63;
    const int wv   = threadIdx.x >> 6;
    const int row  = blockIdx.x * 4 + wv;
    float bv; int bi;
    if (lane < 16) {
        float2 p = pairs[(size_t)row * 16 + lane];
        bv = p.x; bi = __float_as_int(p.y);
    } else {
        bv = __int_as_float(0x7f800000);  // +inf
        bi = 0x7fffffff;
    }
    #pragma unroll
    for (int d = 1; d < 64; d <<= 1) {
        float ov = __shfl_xor(bv, d);
        int   oi = __shfl_xor(bi, d);
        if (ov < bv || (ov == bv && oi < bi)) { bv = ov; bi = oi; }
    }
    s16x8 xv = *(const s16x8*)(Xb + (size_t)row * DIM + lane * 8);
    s16x8 wvv = *(const s16x8*)(Wb + (size_t)bi * DIM + lane * 8);
    float s = 0.f;
    #pragma unroll
    for (int j = 0; j < 8; ++j) {
        float dx = bf2f(xv[j]) - bf2f(wvv[j]);
        s += dx * dx;
    }
    #pragma unroll
    for (int d = 1; d < 64; d <<= 1) s += __shfl_xor(s, d);
    if (lane == 0) psum[wv] = s;
    __syncthreads();
    if (threadIdx.x == 0)
        partial[blockIdx.x] = psum[0] + psum[1] + psum[2] + psum[3];
}

// ---------------- K4: final mean over 8192 partials (double accum) ----------------
__global__ void __launch_bounds__(256)
finalize(const float* __restrict__ partial, float* __restrict__ out) {
    __shared__ double sm[256];
    const float4* p = (const float4*)partial;   // 2048 float4s
    double s = 0.0;
    #pragma unroll
    for (int i = 0; i < 8; ++i) {
        float4 v = p[threadIdx.x + i * 256];
        s += (double)v.x + (double)v.y + (double)v.z + (double)v.w;
    }
    sm[threadIdx.x] = s;
    __syncthreads();
    for (int st = 128; st > 0; st >>= 1) {
        if (threadIdx.x < st) sm[threadIdx.x] += sm[threadIdx.x + st];
        __syncthreads();
    }
    if (threadIdx.x == 0)
        out[0] = (float)(sm[0] / (double)((size_t)N_ROWS * DIM));
}

extern "C" void kernel_launch(void* const* d_in, const int* in_sizes, int n_in,
                              void* d_out, int out_size, void* d_ws, size_t ws_size,
                              hipStream_t stream) {
    const float* X = (const float*)d_in[0];   // [32768][512]
    const float* W = (const float*)d_in[1];   // [1024][512]
    char* ws = (char*)d_ws;
    short*  Xb      = (short*)ws;                          // 32 MB @ 0
    short*  Wb      = (short*)(ws + 33554432);             // 1 MB
    float*  wnorm   = (float*)(ws + 34603008);             // 4 KB
    float2* pairs   = (float2*)(ws + 34607104);            // 4 MB
    float*  partial = (float*)(ws + 38801408);             // 32 KB
    float*  out     = (float*)d_out;

    convertX<<<N_ROWS * DIM / (256 * 8), 256, 0, stream>>>(X, Xb);
    convertW<<<N_CODES / 4, 256, 0, stream>>>(W, Wb, wnorm);
    gemm_argmin<<<2048, 256, 0, stream>>>(Xb, Wb, wnorm, pairs);
    combine_loss<<<N_ROWS / 4, 256, 0, stream>>>(Xb, Wb, pairs, partial);
    finalize<<<1, 256, 0, stream>>>(partial, out);
}